// Round 4
// baseline (98.267 us; speedup 1.0000x reference)
//
#include <hip/hip_runtime.h>

// QuantumAttention: B=8, S=2048, E=8, H=2, D=4, NQ=8
//
// R1 (41us, LDS-broadcast/row) vs R3 (37us, LDS amortized 8 rows/lane) were
// nearly identical despite removing the dominant modeled LDS term -> the
// shared per-pair v_exp_f32 is the hidden bottleneck (effective ~50-70
// cyc/wave-op, not the assumed 8). R4: polynomial exp2 on the full-rate VALU
// (rndne/sub/3*fma/cvt/ldexp, zero trans ops) + occupancy 2->4 blocks/CU.
//
// Quantum circuit closed-form: c_w = cos(tok[w]+tok[w%4]);
// z[0]=c1..c7, z[q>=1]=c0..cq. Softmax one-pass (|s_log2|<~18, fp32 safe);
// 0.5*log2(e) folded into Wq so scores are already log2-domain.

#define SS 2048
#define EE 8

__device__ __forceinline__ float fast_exp2(float s) {
    const float n = rintf(s);                 // v_rndne_f32
    const float f = s - n;                    // f in [-0.5, 0.5]
    float p = fmaf(f, 0.05550411f, 0.24022651f);
    p = fmaf(f, p, 0.69314718f);
    p = fmaf(f, p, 1.0f);
    return __builtin_amdgcn_ldexpf(p, (int)n); // v_cvt_i32_f32 + v_ldexp_f32
}

// grid 1024: bid = b<<7 | h<<6 | rt<<4 | jw.  256 threads = 4 waves.
// Block: rows rt*512..+511 (8 per lane), j-window jw*128..+127 (32 per wave).
extern "C" __global__ __launch_bounds__(256, 4)
void qa_attn4(const float* __restrict__ x, const float* __restrict__ Wq,
              const float* __restrict__ Wk, const float* __restrict__ Wv,
              float* __restrict__ wsD, float4* __restrict__ wsA) {
    __shared__ float wrow[96];                    // wq'(scaled), wk, wv
    __shared__ __align__(16) float4 kv4[256];     // 128 j x {K4,V4} = 4 KB
    __shared__ float rden[3 * 512];               // waves 1..3 partials, 6 KB
    __shared__ __align__(16) float4 racc[3 * 512];// 24 KB

    const int bid = blockIdx.x;
    const int jw = bid & 15, rt = (bid >> 4) & 3, h = (bid >> 6) & 1, b = bid >> 7;
    const int tid = threadIdx.x, lane = tid & 63, w = tid >> 6;

    if (tid < 96) {
        const int grp = tid >> 5, d = (tid >> 3) & 3, e = tid & 7;
        const float* W = (grp == 0) ? Wq : (grp == 1 ? Wk : Wv);
        float val = W[(h * 4 + d) * EE + e];
        if (grp == 0) val *= 0.72134752044f;   // 0.5 * log2(e)
        wrow[tid] = val;
    }
    __syncthreads();   // wrow ready (needed by staging + q)

    // ---- stage K,V for the 128-j window ----
    if (tid < 128) {
        const int j = jw * 128 + tid;
        const float* xp = x + ((size_t)(b * SS + j)) * EE;
        float xv[8];
        *(float4*)&xv[0] = *(const float4*)xp;
        *(float4*)&xv[4] = *(const float4*)(xp + 4);
        float kk[4], vv[4];
        #pragma unroll
        for (int d = 0; d < 4; ++d) {
            float sk = 0.f, sv = 0.f;
            #pragma unroll
            for (int e = 0; e < 8; ++e) {
                sk += xv[e] * wrow[32 + d * 8 + e];
                sv += xv[e] * wrow[64 + d * 8 + e];
            }
            kk[d] = sk; vv[d] = sv;
        }
        kv4[tid * 2]     = make_float4(kk[0], kk[1], kk[2], kk[3]);
        kv4[tid * 2 + 1] = make_float4(vv[0], vv[1], vv[2], vv[3]);
    }

    // ---- q' (log2-scaled) for this lane's 8 rows ----
    float q[8][4];
    const int row0 = rt * 512 + lane;
    #pragma unroll
    for (int m = 0; m < 8; ++m) {
        const float* xp = x + ((size_t)(b * SS + row0 + m * 64)) * EE;
        float xv[8];
        *(float4*)&xv[0] = *(const float4*)xp;
        *(float4*)&xv[4] = *(const float4*)(xp + 4);
        #pragma unroll
        for (int d = 0; d < 4; ++d) {
            float s = 0.f;
            #pragma unroll
            for (int e = 0; e < 8; ++e) s += xv[e] * wrow[d * 8 + e];
            q[m][d] = s;
        }
    }
    __syncthreads();   // kv4 ready

    // ---- 32-j slice for this wave, 8 rows per lane, poly-exp2 ----
    float den[8] = {};
    float acc[8][4] = {};
    const int jb = w * 32;
    #pragma unroll 2
    for (int jl = 0; jl < 32; ++jl) {
        const float4 kk = kv4[(jb + jl) * 2];      // wave-broadcast
        const float4 vv = kv4[(jb + jl) * 2 + 1];
        #pragma unroll
        for (int m = 0; m < 8; ++m) {
            const float s = q[m][0] * kk.x + q[m][1] * kk.y
                          + q[m][2] * kk.z + q[m][3] * kk.w;
            const float e = fast_exp2(s);
            den[m] += e;
            acc[m][0] += e * vv.x; acc[m][1] += e * vv.y;
            acc[m][2] += e * vv.z; acc[m][3] += e * vv.w;
        }
    }

    // ---- single-stage reduce: waves 1..3 park partials, wave 0 merges ----
    if (w > 0) {
        #pragma unroll
        for (int m = 0; m < 8; ++m) {
            rden[(w - 1) * 512 + lane + m * 64] = den[m];
            racc[(w - 1) * 512 + lane + m * 64] =
                make_float4(acc[m][0], acc[m][1], acc[m][2], acc[m][3]);
        }
    }
    __syncthreads();
    if (w == 0) {
        #pragma unroll
        for (int m = 0; m < 8; ++m) {
            const int r = lane + m * 64;
            float d = den[m] + rden[r] + rden[512 + r] + rden[1024 + r];
            float4 a1 = racc[r], a2 = racc[512 + r], a3 = racc[1024 + r];
            float4 a = make_float4(acc[m][0] + a1.x + a2.x + a3.x,
                                   acc[m][1] + a1.y + a2.y + a3.y,
                                   acc[m][2] + a1.z + a2.z + a3.z,
                                   acc[m][3] + a1.w + a2.w + a3.w);
            const size_t idx = ((size_t)((b * 2 + h) * 16 + jw)) * SS + row0 + m * 64;
            wsD[idx] = d;
            wsA[idx] = a;
        }
    }
}

// Merge 16 window-partials per (token, head), divide, closed-form quantum, Wo.
extern "C" __global__ __launch_bounds__(256)
void qa_quantum4(const float* __restrict__ wsD, const float4* __restrict__ wsA,
                 const float* __restrict__ Wo, float* __restrict__ out) {
    __shared__ float wo[64];
    const int tid = threadIdx.x;
    if (tid < 64) wo[tid] = Wo[tid];
    __syncthreads();

    const int g = blockIdx.x * 256 + tid;   // token 0..16383
    const int b = g >> 11, s = g & 2047;

    float tok[8];
    #pragma unroll
    for (int h = 0; h < 2; ++h) {
        float den = 0.f, a0 = 0.f, a1 = 0.f, a2 = 0.f, a3 = 0.f;
        #pragma unroll
        for (int sl = 0; sl < 16; ++sl) {
            const size_t idx = ((size_t)((b * 2 + h) * 16 + sl)) * SS + s;
            den += wsD[idx];
            const float4 p = wsA[idx];
            a0 += p.x; a1 += p.y; a2 += p.z; a3 += p.w;
        }
        const float inv = 1.f / den;
        tok[h * 4 + 0] = a0 * inv; tok[h * 4 + 1] = a1 * inv;
        tok[h * 4 + 2] = a2 * inv; tok[h * 4 + 3] = a3 * inv;
    }

    float c[8];
    #pragma unroll
    for (int ww = 0; ww < 8; ++ww) c[ww] = __cosf(tok[ww] + tok[ww & 3]);

    float z[8];
    float p = 1.f;
    #pragma unroll
    for (int qq = 1; qq < 8; ++qq) { p *= c[qq]; z[qq] = p; }
    z[0] = p;                       // c1..c7
    #pragma unroll
    for (int qq = 1; qq < 8; ++qq) z[qq] *= c[0];   // c0..cq

    float y[8];
    #pragma unroll
    for (int f = 0; f < 8; ++f) {
        float sum = 0.f;
        #pragma unroll
        for (int qq = 0; qq < 8; ++qq) sum += z[qq] * wo[f * 8 + qq];
        y[f] = sum;
    }
    float* op = out + (size_t)g * 8;
    *(float4*)op       = make_float4(y[0], y[1], y[2], y[3]);
    *(float4*)(op + 4) = make_float4(y[4], y[5], y[6], y[7]);
}

extern "C" void kernel_launch(void* const* d_in, const int* in_sizes, int n_in,
                              void* d_out, int out_size, void* d_ws, size_t ws_size,
                              hipStream_t stream) {
    const float* x  = (const float*)d_in[0];
    const float* Wq = (const float*)d_in[1];
    const float* Wk = (const float*)d_in[2];
    const float* Wv = (const float*)d_in[3];
    const float* Wo = (const float*)d_in[4];
    float* out = (float*)d_out;

    float*  wsD = (float*)d_ws;                          // 16bh*16sl*2048 = 2 MB
    float4* wsA = (float4*)((char*)d_ws + (16 * 16 * 2048) * sizeof(float)); // 8 MB

    qa_attn4<<<dim3(1024), dim3(256), 0, stream>>>(x, Wq, Wk, Wv, wsD, wsA);
    qa_quantum4<<<dim3(64), dim3(256), 0, stream>>>(wsD, wsA, Wo, out);
}

// Round 5
// 87.032 us; speedup vs baseline: 1.1291x; 1.1291x over previous
//
#include <hip/hip_runtime.h>

// QuantumAttention: B=8, S=2048, E=8, H=2, D=4, NQ=8
//
// History: R1 41us (LDS broadcast/row), R3 36us (8 rows/lane), R4 regressed
// (3 confounded changes; likely VGPR spill under (256,4) cap with ~120 live).
// VALU-count models predict 9-11us for R3 => the ~3x gap is in-order issue
// dependency stalls at only 2 waves/SIMD. R5: M=4 rows/lane (~70 VGPRs, no
// spill under (256,4)), 23KB LDS, 1024 blocks -> 4 blocks/CU = 4 waves/SIMD.
//
// Quantum circuit closed-form: c_w = cos(tok[w]+tok[w%4]);
// z[0]=c1..c7, z[q>=1]=c0..cq. Softmax one-pass (scores bounded, fp32 safe);
// 0.5*log2(e) folded into Wq so inner exp is bare v_exp_f32 (exp2).

#define SS 2048
#define EE 8

// grid 1024: bid = b<<7 | h<<6 | rt<<3 | jw.  256 threads = 4 waves.
// Block: rows rt*256..+255 (4 per lane), j-window jw*256..+255 (64 per wave).
extern "C" __global__ __launch_bounds__(256, 4)
void qa_attn5(const float* __restrict__ x, const float* __restrict__ Wq,
              const float* __restrict__ Wk, const float* __restrict__ Wv,
              float* __restrict__ wsD, float4* __restrict__ wsA) {
    __shared__ float wrow[96];                    // wq'(scaled), wk, wv
    __shared__ __align__(16) float4 kv4[512];     // 256 j x {K4,V4} = 8 KB
    __shared__ float rden[3 * 256];               // waves 1..3 partials, 3 KB
    __shared__ __align__(16) float4 racc[3 * 256];// 12 KB

    const int bid = blockIdx.x;
    const int jw = bid & 7, rt = (bid >> 3) & 7, h = (bid >> 6) & 1, b = bid >> 7;
    const int tid = threadIdx.x, lane = tid & 63, w = tid >> 6;

    if (tid < 96) {
        const int grp = tid >> 5, d = (tid >> 3) & 3, e = tid & 7;
        const float* W = (grp == 0) ? Wq : (grp == 1 ? Wk : Wv);
        float val = W[(h * 4 + d) * EE + e];
        if (grp == 0) val *= 0.72134752044f;   // 0.5 * log2(e)
        wrow[tid] = val;
    }
    __syncthreads();   // wrow ready

    // ---- stage K,V for the 256-j window (one j per thread) ----
    {
        const int j = jw * 256 + tid;
        const float* xp = x + ((size_t)(b * SS + j)) * EE;
        float xv[8];
        *(float4*)&xv[0] = *(const float4*)xp;
        *(float4*)&xv[4] = *(const float4*)(xp + 4);
        float kk[4], vv[4];
        #pragma unroll
        for (int d = 0; d < 4; ++d) {
            float sk = 0.f, sv = 0.f;
            #pragma unroll
            for (int e = 0; e < 8; ++e) {
                sk += xv[e] * wrow[32 + d * 8 + e];
                sv += xv[e] * wrow[64 + d * 8 + e];
            }
            kk[d] = sk; vv[d] = sv;
        }
        kv4[tid * 2]     = make_float4(kk[0], kk[1], kk[2], kk[3]);
        kv4[tid * 2 + 1] = make_float4(vv[0], vv[1], vv[2], vv[3]);
    }

    // ---- q' (log2-scaled) for this lane's 4 rows ----
    float q[4][4];
    const int row0 = rt * 256 + lane;
    #pragma unroll
    for (int m = 0; m < 4; ++m) {
        const float* xp = x + ((size_t)(b * SS + row0 + m * 64)) * EE;
        float xv[8];
        *(float4*)&xv[0] = *(const float4*)xp;
        *(float4*)&xv[4] = *(const float4*)(xp + 4);
        #pragma unroll
        for (int d = 0; d < 4; ++d) {
            float s = 0.f;
            #pragma unroll
            for (int e = 0; e < 8; ++e) s += xv[e] * wrow[d * 8 + e];
            q[m][d] = s;
        }
    }
    __syncthreads();   // kv4 ready

    // ---- 64-j slice for this wave, 4 rows per lane ----
    float den[4] = {};
    float acc[4][4] = {};
    const int jb = w * 64;
    #pragma unroll 2
    for (int jl = 0; jl < 64; ++jl) {
        const float4 kk = kv4[(jb + jl) * 2];      // wave-broadcast
        const float4 vv = kv4[(jb + jl) * 2 + 1];
        #pragma unroll
        for (int m = 0; m < 4; ++m) {
            const float s = q[m][0] * kk.x + q[m][1] * kk.y
                          + q[m][2] * kk.z + q[m][3] * kk.w;
            const float e = __builtin_amdgcn_exp2f(s);
            den[m] += e;
            acc[m][0] += e * vv.x; acc[m][1] += e * vv.y;
            acc[m][2] += e * vv.z; acc[m][3] += e * vv.w;
        }
    }

    // ---- single-stage reduce: waves 1..3 park, wave 0 merges + writes ----
    if (w > 0) {
        #pragma unroll
        for (int m = 0; m < 4; ++m) {
            rden[(w - 1) * 256 + lane + m * 64] = den[m];
            racc[(w - 1) * 256 + lane + m * 64] =
                make_float4(acc[m][0], acc[m][1], acc[m][2], acc[m][3]);
        }
    }
    __syncthreads();
    if (w == 0) {
        #pragma unroll
        for (int m = 0; m < 4; ++m) {
            const int r = lane + m * 64;
            float d = den[m] + rden[r] + rden[256 + r] + rden[512 + r];
            float4 a1 = racc[r], a2 = racc[256 + r], a3 = racc[512 + r];
            float4 a = make_float4(acc[m][0] + a1.x + a2.x + a3.x,
                                   acc[m][1] + a1.y + a2.y + a3.y,
                                   acc[m][2] + a1.z + a2.z + a3.z,
                                   acc[m][3] + a1.w + a2.w + a3.w);
            const size_t idx = ((size_t)((b * 2 + h) * 8 + jw)) * SS + row0 + m * 64;
            wsD[idx] = d;
            wsA[idx] = a;
        }
    }
}

// Merge 8 window-partials per (token, head), divide, closed-form quantum, Wo.
extern "C" __global__ __launch_bounds__(256)
void qa_quantum5(const float* __restrict__ wsD, const float4* __restrict__ wsA,
                 const float* __restrict__ Wo, float* __restrict__ out) {
    __shared__ float wo[64];
    const int tid = threadIdx.x;
    if (tid < 64) wo[tid] = Wo[tid];
    __syncthreads();

    const int g = blockIdx.x * 256 + tid;   // token 0..16383
    const int b = g >> 11, s = g & 2047;

    float tok[8];
    #pragma unroll
    for (int h = 0; h < 2; ++h) {
        float den = 0.f, a0 = 0.f, a1 = 0.f, a2 = 0.f, a3 = 0.f;
        #pragma unroll
        for (int sl = 0; sl < 8; ++sl) {
            const size_t idx = ((size_t)((b * 2 + h) * 8 + sl)) * SS + s;
            den += wsD[idx];
            const float4 p = wsA[idx];
            a0 += p.x; a1 += p.y; a2 += p.z; a3 += p.w;
        }
        const float inv = 1.f / den;
        tok[h * 4 + 0] = a0 * inv; tok[h * 4 + 1] = a1 * inv;
        tok[h * 4 + 2] = a2 * inv; tok[h * 4 + 3] = a3 * inv;
    }

    float c[8];
    #pragma unroll
    for (int ww = 0; ww < 8; ++ww) c[ww] = __cosf(tok[ww] + tok[ww & 3]);

    float z[8];
    float p = 1.f;
    #pragma unroll
    for (int qq = 1; qq < 8; ++qq) { p *= c[qq]; z[qq] = p; }
    z[0] = p;                       // c1..c7
    #pragma unroll
    for (int qq = 1; qq < 8; ++qq) z[qq] *= c[0];   // c0..cq

    float y[8];
    #pragma unroll
    for (int f = 0; f < 8; ++f) {
        float sum = 0.f;
        #pragma unroll
        for (int qq = 0; qq < 8; ++qq) sum += z[qq] * wo[f * 8 + qq];
        y[f] = sum;
    }
    float* op = out + (size_t)g * 8;
    *(float4*)op       = make_float4(y[0], y[1], y[2], y[3]);
    *(float4*)(op + 4) = make_float4(y[4], y[5], y[6], y[7]);
}

extern "C" void kernel_launch(void* const* d_in, const int* in_sizes, int n_in,
                              void* d_out, int out_size, void* d_ws, size_t ws_size,
                              hipStream_t stream) {
    const float* x  = (const float*)d_in[0];
    const float* Wq = (const float*)d_in[1];
    const float* Wk = (const float*)d_in[2];
    const float* Wv = (const float*)d_in[3];
    const float* Wo = (const float*)d_in[4];
    float* out = (float*)d_out;

    float*  wsD = (float*)d_ws;                          // 16*8*2048 floats = 1 MB
    float4* wsA = (float4*)((char*)d_ws + (16 * 8 * 2048) * sizeof(float)); // 4 MB

    qa_attn5<<<dim3(1024), dim3(256), 0, stream>>>(x, Wq, Wk, Wv, wsD, wsA);
    qa_quantum5<<<dim3(64), dim3(256), 0, stream>>>(wsD, wsA, Wo, out);
}